// Round 1
// baseline (115.241 us; speedup 1.0000x reference)
//
#include <hip/hip_runtime.h>
#include <hip/hip_bf16.h>

#define CIN   64
#define COUT  128
#define TT    256
#define VV    25
#define TV    (TT * VV)   // 6400
#define KW    9
#define PAD   4

// ---------------- Kernel A: 1x1 conv + folded BatchNorm ----------------
// grid: (TV/256 = 25, 2 output-channel halves, N=16); block: 256 threads.
// Each thread owns one (t,v) position: x column (64 ch) in registers,
// computes 64 output channels with W staged in LDS (broadcast reads).
__global__ __launch_bounds__(256) void conv_bn_kernel(
    const float* __restrict__ x, const float* __restrict__ w,
    const float* __restrict__ cb, const float* __restrict__ gamma,
    const float* __restrict__ beta, const float* __restrict__ rm,
    const float* __restrict__ rv, float* __restrict__ y)
{
    __shared__ float wl[64][CIN];     // 16 KB
    __shared__ float sc[64];          // BN scale
    __shared__ float of[64];          // folded offset (bias*scale + beta - rm*scale)

    const int chunk = blockIdx.x;     // 0..24
    const int oh    = blockIdx.y;     // 0..1
    const int n     = blockIdx.z;     // 0..15
    const int tid   = threadIdx.x;

    for (int i = tid; i < 64 * CIN; i += 256) {
        const int o = i >> 6, c = i & 63;
        wl[o][c] = w[(size_t)(oh * 64 + o) * CIN + c];
    }
    if (tid < 64) {
        const int o = oh * 64 + tid;
        const float s = gamma[o] * rsqrtf(rv[o] + 1e-5f);
        sc[tid] = s;
        of[tid] = cb[o] * s + beta[o] - rm[o] * s;
    }
    __syncthreads();

    const int tv = chunk * 256 + tid;
    const float* xp = x + (size_t)n * CIN * TV + tv;
    float xr[CIN];
#pragma unroll
    for (int c = 0; c < CIN; ++c) xr[c] = xp[(size_t)c * TV];

    float* yp = y + (size_t)n * COUT * TV + (size_t)oh * 64 * TV + tv;
#pragma unroll 4
    for (int o = 0; o < 64; ++o) {
        float acc = 0.f;
#pragma unroll
        for (int c = 0; c < CIN; ++c) acc = fmaf(xr[c], wl[o][c], acc);
        yp[(size_t)o * TV] = acc * sc[o] + of[o];
    }
}

// ---------------- Kernel B: temporal-window attention ----------------
// grid: N*COUT = 2048 blocks; block: 256 threads, one t per thread.
// Whole y[n,c] row (256 x 25 fp32 = 25.6 KB) staged in LDS.
__global__ __launch_bounds__(256) void attn_kernel(
    const float* __restrict__ y, const float* __restrict__ att0,
    float* __restrict__ out)
{
    __shared__ float yl[TT * VV];     // 25.6 KB
    __shared__ float a0[KW];

    const int nc  = blockIdx.x;       // n*COUT + c
    const int c   = nc & (COUT - 1);
    const int tid = threadIdx.x;      // t

    const float* yp = y + (size_t)nc * TV;
    for (int i = tid; i < TV; i += 256) yl[i] = yp[i];
    if (tid < KW) a0[tid] = att0[c * KW + tid];
    __syncthreads();

    const float* yc = &yl[tid * VV];

    // scores: dot(y[t], y[t+u-4]) / V ; zero rows (padding) give score 0
    float s[KW];
#pragma unroll
    for (int u = 0; u < KW; ++u) {
        const int tt = tid + u - PAD;
        float acc = 0.f;
        if (tt >= 0 && tt < TT) {
            const float* yu = &yl[tt * VV];
#pragma unroll
            for (int v = 0; v < VV; ++v) acc = fmaf(yc[v], yu[v], acc);
        }
        s[u] = acc * (1.0f / (float)VV);
    }

    // softmax over the 9 positions (zeros included), then + att0
    float m = s[0];
#pragma unroll
    for (int u = 1; u < KW; ++u) m = fmaxf(m, s[u]);
    float den = 0.f;
#pragma unroll
    for (int u = 0; u < KW; ++u) { s[u] = __expf(s[u] - m); den += s[u]; }
    const float inv = 1.f / den;
    float att[KW];
#pragma unroll
    for (int u = 0; u < KW; ++u) att[u] = s[u] * inv + a0[u];

    // out[t, v] = sum_u att[u] * y[t+u-4, v]
    float o[VV];
#pragma unroll
    for (int v = 0; v < VV; ++v) o[v] = 0.f;
#pragma unroll
    for (int u = 0; u < KW; ++u) {
        const int tt = tid + u - PAD;
        if (tt >= 0 && tt < TT) {
            const float* yu = &yl[tt * VV];
            const float a = att[u];
#pragma unroll
            for (int v = 0; v < VV; ++v) o[v] = fmaf(a, yu[v], o[v]);
        }
    }

    float* op = out + (size_t)nc * TV + tid * VV;
#pragma unroll
    for (int v = 0; v < VV; ++v) op[v] = o[v];
}

extern "C" void kernel_launch(void* const* d_in, const int* in_sizes, int n_in,
                              void* d_out, int out_size, void* d_ws, size_t ws_size,
                              hipStream_t stream)
{
    const float* x     = (const float*)d_in[0];
    const float* w     = (const float*)d_in[1];
    const float* cb    = (const float*)d_in[2];
    const float* gamma = (const float*)d_in[3];
    const float* beta  = (const float*)d_in[4];
    const float* rm    = (const float*)d_in[5];
    const float* rv    = (const float*)d_in[6];
    const float* att0  = (const float*)d_in[7];
    float* out = (float*)d_out;
    float* y   = (float*)d_ws;   // 16*128*6400*4 = 52.4 MB scratch

    dim3 gA(TV / 256, 2, 16);
    conv_bn_kernel<<<gA, 256, 0, stream>>>(x, w, cb, gamma, beta, rm, rv, y);

    dim3 gB(16 * COUT);
    attn_kernel<<<gB, 256, 0, stream>>>(y, att0, out);
}

// Round 2
// 79.886 us; speedup vs baseline: 1.4426x; 1.4426x over previous
//
#include <hip/hip_runtime.h>
#include <hip/hip_bf16.h>

#define CIN   64
#define COUT  128
#define TT    256
#define VV    25
#define TV    (TT * VV)   // 6400
#define KW    9
#define PAD   4
#define RS    28          // padded LDS row stride (floats): 16B-aligned, bank-balanced

// ---------------- Kernel A: 1x1 conv + folded BatchNorm ----------------
// grid: (25, 2, 16); block 256. Each thread owns one (t,v): x column in VGPRs,
// weights streamed through the SCALAR path (uniform index -> s_load; FMA reads SGPR).
__global__ __launch_bounds__(256) void conv_bn_kernel(
    const float* __restrict__ x, const float* __restrict__ w,
    const float* __restrict__ cb, const float* __restrict__ gamma,
    const float* __restrict__ beta, const float* __restrict__ rm,
    const float* __restrict__ rv, float* __restrict__ y)
{
    __shared__ float sc[64];
    __shared__ float of[64];

    const int chunk = blockIdx.x;     // 0..24
    const int oh    = blockIdx.y;     // 0..1
    const int n     = blockIdx.z;     // 0..15
    const int tid   = threadIdx.x;

    if (tid < 64) {
        const int o = oh * 64 + tid;
        const float s = gamma[o] * rsqrtf(rv[o] + 1e-5f);
        sc[tid] = s;
        of[tid] = cb[o] * s + beta[o] - rm[o] * s;
    }
    __syncthreads();

    const int tv = chunk * 256 + tid;
    const float* xp = x + (size_t)n * CIN * TV + tv;
    float xr[CIN];
#pragma unroll
    for (int c = 0; c < CIN; ++c) xr[c] = xp[(size_t)c * TV];

    const float* wb = w + (size_t)oh * 64 * CIN;  // this block's 64x64 weight tile
    float* yp = y + (size_t)n * COUT * TV + (size_t)oh * 64 * TV + tv;

    for (int og = 0; og < 64; og += 8) {
        const float* wo = wb + og * CIN;          // wave-uniform base
        float acc[8] = {0.f, 0.f, 0.f, 0.f, 0.f, 0.f, 0.f, 0.f};
#pragma unroll
        for (int c = 0; c < CIN; ++c) {
            const float xc = xr[c];
#pragma unroll
            for (int j = 0; j < 8; ++j)
                acc[j] = fmaf(xc, wo[j * CIN + c], acc[j]);  // uniform -> SGPR operand
        }
#pragma unroll
        for (int j = 0; j < 8; ++j)
            yp[(size_t)(og + j) * TV] = acc[j] * sc[og + j] + of[og + j];
    }
}

// ---------------- Kernel B: temporal-window attention ----------------
// grid: N*COUT = 2048 blocks; block 128 threads; each thread computes TWO
// adjacent t (windows share 8/10 rows). Rows padded to 28 floats -> float4
// LDS reads (ds_read_b128), bank-balanced (stride 28 dwords == 4 mod 32).
__global__ __launch_bounds__(128) void attn_kernel(
    const float* __restrict__ y, const float* __restrict__ att0,
    float* __restrict__ out)
{
    __shared__ float yl[TT * RS];     // 28672 B
    __shared__ float a0s[KW];

    const int nc  = blockIdx.x;       // n*COUT + c
    const int c   = nc & (COUT - 1);
    const int tid = threadIdx.x;

    const float* yp = y + (size_t)nc * TV;

    // zero the 3 pad slots of each row
    for (int j = tid; j < TT * 3; j += 128) {
        const int t = j / 3, p = j - t * 3;
        yl[t * RS + 25 + p] = 0.f;
    }
    // stage y -> strided rows
    for (int i = tid; i < TV; i += 128) {
        const int t = i / 25, v = i - t * 25;
        yl[t * RS + v] = yp[i];
    }
    if (tid < KW) a0s[tid] = att0[c * KW + tid];
    __syncthreads();

    const int t0 = tid * 2, t1 = t0 + 1;

    float4 yc0[7], yc1[7];
    {
        const float4* r0 = (const float4*)&yl[t0 * RS];
        const float4* r1 = (const float4*)&yl[t1 * RS];
#pragma unroll
        for (int k = 0; k < 7; ++k) { yc0[k] = r0[k]; yc1[k] = r1[k]; }
    }

    // ---- scores (zero rows of the padding give score 0, kept in softmax) ----
    float s0[KW], s1[KW];
#pragma unroll
    for (int u = 0; u < KW; ++u) { s0[u] = 0.f; s1[u] = 0.f; }

#pragma unroll
    for (int j = 0; j < 10; ++j) {
        const int r = t0 - PAD + j;
        if (r >= 0 && r < TT) {
            const float4* rw = (const float4*)&yl[r * RS];
            float d0 = 0.f, d1 = 0.f;
#pragma unroll
            for (int k = 0; k < 7; ++k) {
                const float4 q = rw[k];
                d0 = fmaf(q.x, yc0[k].x, d0); d0 = fmaf(q.y, yc0[k].y, d0);
                d0 = fmaf(q.z, yc0[k].z, d0); d0 = fmaf(q.w, yc0[k].w, d0);
                d1 = fmaf(q.x, yc1[k].x, d1); d1 = fmaf(q.y, yc1[k].y, d1);
                d1 = fmaf(q.z, yc1[k].z, d1); d1 = fmaf(q.w, yc1[k].w, d1);
            }
            if (j <= 8) s0[j]     = d0 * (1.f / (float)VV);
            if (j >= 1) s1[j - 1] = d1 * (1.f / (float)VV);
        }
    }

    // ---- softmax over 9 + att0 ----
    float aw0[KW], aw1[KW];
    {
        float m0 = s0[0], m1 = s1[0];
#pragma unroll
        for (int u = 1; u < KW; ++u) { m0 = fmaxf(m0, s0[u]); m1 = fmaxf(m1, s1[u]); }
        float d0 = 0.f, d1 = 0.f;
#pragma unroll
        for (int u = 0; u < KW; ++u) {
            aw0[u] = __expf(s0[u] - m0); d0 += aw0[u];
            aw1[u] = __expf(s1[u] - m1); d1 += aw1[u];
        }
        const float i0 = 1.f / d0, i1 = 1.f / d1;
#pragma unroll
        for (int u = 0; u < KW; ++u) {
            aw0[u] = aw0[u] * i0 + a0s[u];
            aw1[u] = aw1[u] * i1 + a0s[u];
        }
    }

    // ---- output: out[t] = sum_u aw[u] * y[t+u-4] ----
    float4 o0[7], o1[7];
#pragma unroll
    for (int k = 0; k < 7; ++k) {
        o0[k] = make_float4(0.f, 0.f, 0.f, 0.f);
        o1[k] = make_float4(0.f, 0.f, 0.f, 0.f);
    }
#pragma unroll
    for (int j = 0; j < 10; ++j) {
        const int r = t0 - PAD + j;
        if (r >= 0 && r < TT) {
            const float4* rw = (const float4*)&yl[r * RS];
#pragma unroll
            for (int k = 0; k < 7; ++k) {
                const float4 q = rw[k];
                if (j <= 8) {
                    const float a = aw0[j];
                    o0[k].x = fmaf(a, q.x, o0[k].x); o0[k].y = fmaf(a, q.y, o0[k].y);
                    o0[k].z = fmaf(a, q.z, o0[k].z); o0[k].w = fmaf(a, q.w, o0[k].w);
                }
                if (j >= 1) {
                    const float a = aw1[j - 1];
                    o1[k].x = fmaf(a, q.x, o1[k].x); o1[k].y = fmaf(a, q.y, o1[k].y);
                    o1[k].z = fmaf(a, q.z, o1[k].z); o1[k].w = fmaf(a, q.w, o1[k].w);
                }
            }
        }
    }

    // ---- overlay packed output in LDS, then coalesced float4 stores ----
    __syncthreads();
    {
        float* op0 = &yl[t0 * VV];
        float* op1 = &yl[t1 * VV];
#pragma unroll
        for (int k = 0; k < 6; ++k) {
            op0[4*k+0] = o0[k].x; op0[4*k+1] = o0[k].y; op0[4*k+2] = o0[k].z; op0[4*k+3] = o0[k].w;
            op1[4*k+0] = o1[k].x; op1[4*k+1] = o1[k].y; op1[4*k+2] = o1[k].z; op1[4*k+3] = o1[k].w;
        }
        op0[24] = o0[6].x;
        op1[24] = o1[6].x;
    }
    __syncthreads();
    {
        float4* og = (float4*)(out + (size_t)nc * TV);
        const float4* yl4 = (const float4*)yl;
        for (int i = tid; i < TV / 4; i += 128) og[i] = yl4[i];
    }
}

extern "C" void kernel_launch(void* const* d_in, const int* in_sizes, int n_in,
                              void* d_out, int out_size, void* d_ws, size_t ws_size,
                              hipStream_t stream)
{
    const float* x     = (const float*)d_in[0];
    const float* w     = (const float*)d_in[1];
    const float* cb    = (const float*)d_in[2];
    const float* gamma = (const float*)d_in[3];
    const float* beta  = (const float*)d_in[4];
    const float* rm    = (const float*)d_in[5];
    const float* rv    = (const float*)d_in[6];
    const float* att0  = (const float*)d_in[7];
    float* out = (float*)d_out;
    float* y   = (float*)d_ws;   // 16*128*6400*4 = 52.4 MB scratch

    dim3 gA(TV / 256, 2, 16);
    conv_bn_kernel<<<gA, 256, 0, stream>>>(x, w, cb, gamma, beta, rm, rv, y);

    dim3 gB(16 * COUT);
    attn_kernel<<<gB, 128, 0, stream>>>(y, att0, out);
}

// Round 3
// 47.272 us; speedup vs baseline: 2.4378x; 1.6899x over previous
//
#include <hip/hip_runtime.h>
#include <hip/hip_bf16.h>

#define CIN   64
#define COUT  128
#define TT    256
#define VV    25
#define TV    (TT * VV)   // 6400
#define KW    9
#define PAD   4
#define RS    28          // attn LDS row stride (floats)

typedef __attribute__((ext_vector_type(8))) short short8;   // 8 bf16 (4 VGPRs)
typedef __attribute__((ext_vector_type(4))) float f32x4;

__device__ __forceinline__ unsigned f2b(float f) {          // fp32 -> bf16 bits (RNE)
    unsigned u = __builtin_bit_cast(unsigned, f);
    return (u + 0x7FFFu + ((u >> 16) & 1u)) >> 16;
}
__device__ __forceinline__ float b2f(unsigned short u) {    // bf16 bits -> fp32 (exact)
    unsigned v = (unsigned)u << 16;
    return __builtin_bit_cast(float, v);
}
// XOR-swizzled byte offset inside a [row][128B] LDS tile (G4: break the
// 128B-row-stride 16-way bank conflict on ds_read_b128)
__device__ __forceinline__ int swz(int row, int cbyte) {
    return row * 128 + ((cbyte & ~15) ^ ((row & 7) << 4)) + (cbyte & 15);
}

// ---------------- Kernel A: 1x1 conv + BN via bf16 MFMA ----------------
// grid (50 pos-chunks, 16 n); block 256 = 4 waves.
// Y[128 x 6400] = W[128x64] @ X[64x6400] per n; K=64 -> 2 MFMA(16x16x32) steps.
// W LDS [o][c] bf16 (k-contiguous), X LDS transposed [pos][c] bf16 (k-contiguous),
// both XOR-swizzled. Wave w computes rows w*32..w*32+31 x all 128 pos.
__global__ __launch_bounds__(256) void conv_mfma(
    const float* __restrict__ x, const float* __restrict__ w,
    const float* __restrict__ cb, const float* __restrict__ gamma,
    const float* __restrict__ beta, const float* __restrict__ rm,
    const float* __restrict__ rv, unsigned short* __restrict__ y)
{
    __shared__ __align__(16) unsigned short Wl[COUT * 64];   // 16 KB, swizzled
    __shared__ __align__(16) unsigned short Xl[128 * 64];    // 16 KB, swizzled [pos][c]
    __shared__ float sc[COUT];
    __shared__ float of[COUT];

    const int pc  = blockIdx.x;       // 0..49
    const int n   = blockIdx.y;       // 0..15
    const int tid = threadIdx.x;
    const int posbase = pc * 128;

    if (tid < COUT) {
        const float s = gamma[tid] * rsqrtf(rv[tid] + 1e-5f);
        sc[tid] = s;
        of[tid] = cb[tid] * s + beta[tid] - rm[tid] * s;
    }
    // stage W: lanes sweep c4 fastest -> coalesced float4 reads
    for (int idx = tid; idx < 2048; idx += 256) {
        const int c4 = idx & 15, o = idx >> 4;
        const f32x4 wv = *(const f32x4*)(w + o * 64 + c4 * 4);
        uint2 pk;
        pk.x = f2b(wv.x) | (f2b(wv.y) << 16);
        pk.y = f2b(wv.z) | (f2b(wv.w) << 16);
        *(uint2*)((char*)Wl + swz(o, c4 * 8)) = pk;
    }
    // stage X transposed: lanes sweep pos fastest -> coalesced dword reads
    for (int idx = tid; idx < 2048; idx += 256) {
        const int pos = idx & 127, c4 = idx >> 7;
        const float* xp = x + (size_t)n * CIN * TV + (size_t)(c4 * 4) * TV + posbase + pos;
        const float a0 = xp[0], a1 = xp[TV], a2 = xp[2 * TV], a3 = xp[3 * TV];
        uint2 pk;
        pk.x = f2b(a0) | (f2b(a1) << 16);
        pk.y = f2b(a2) | (f2b(a3) << 16);
        *(uint2*)((char*)Xl + swz(pos, c4 * 8)) = pk;
    }
    __syncthreads();

    const int wv_ = tid >> 6, lane = tid & 63;
    const int lr = lane & 15, lh = lane >> 4;   // lh in 0..3

    // A fragments: W[o = w*32+m0*16+lr][k = lh*8 + kh*32 + 0..7] -> ds_read_b128
    short8 afr[2][2];
#pragma unroll
    for (int m0 = 0; m0 < 2; ++m0)
#pragma unroll
        for (int kh = 0; kh < 2; ++kh)
            afr[m0][kh] = *(const short8*)((const char*)Wl +
                              swz(wv_ * 32 + m0 * 16 + lr, kh * 64 + lh * 16));

    f32x4 acc[2][8];
#pragma unroll
    for (int m0 = 0; m0 < 2; ++m0)
#pragma unroll
        for (int n0 = 0; n0 < 8; ++n0) acc[m0][n0] = (f32x4){0.f, 0.f, 0.f, 0.f};

#pragma unroll
    for (int n0 = 0; n0 < 8; ++n0) {
        const int prow = n0 * 16 + lr;
        const short8 b0 = *(const short8*)((const char*)Xl + swz(prow, lh * 16));
        const short8 b1 = *(const short8*)((const char*)Xl + swz(prow, 64 + lh * 16));
#pragma unroll
        for (int m0 = 0; m0 < 2; ++m0) {
            acc[m0][n0] = __builtin_amdgcn_mfma_f32_16x16x32_bf16(afr[m0][0], b0, acc[m0][n0], 0, 0, 0);
            acc[m0][n0] = __builtin_amdgcn_mfma_f32_16x16x32_bf16(afr[m0][1], b1, acc[m0][n0], 0, 0, 0);
        }
    }

    // epilogue: D[o][pos], o = w*32+m0*16+lh*4+r, pos = n0*16+lr (m89 C/D layout)
    unsigned short* yb = y + (size_t)n * COUT * TV + posbase;
#pragma unroll
    for (int m0 = 0; m0 < 2; ++m0)
#pragma unroll
        for (int n0 = 0; n0 < 8; ++n0)
#pragma unroll
            for (int r = 0; r < 4; ++r) {
                const int o = wv_ * 32 + m0 * 16 + lh * 4 + r;
                const int pos = n0 * 16 + lr;
                const float val = acc[m0][n0][r] * sc[o] + of[o];
                yb[(size_t)o * TV + pos] = (unsigned short)f2b(val);
            }
}

// ---------------- Kernel B: temporal-window attention (bf16 y in) ----------------
__global__ __launch_bounds__(128) void attn_kernel(
    const unsigned short* __restrict__ y, const float* __restrict__ att0,
    float* __restrict__ out)
{
    __shared__ float yl[TT * RS];     // 28672 B
    __shared__ float a0s[KW];

    const int nc  = blockIdx.x;       // n*COUT + c
    const int c   = nc & (COUT - 1);
    const int tid = threadIdx.x;

    const unsigned short* yp = y + (size_t)nc * TV;

    for (int j = tid; j < TT * 3; j += 128) {
        const int t = j / 3, p = j - t * 3;
        yl[t * RS + 25 + p] = 0.f;
    }
    for (int i = tid; i < TV / 4; i += 128) {     // 1600 ushort4 loads
        const ushort4 u = *(const ushort4*)(yp + i * 4);
        const int e = i * 4;
        const float f[4] = { b2f(u.x), b2f(u.y), b2f(u.z), b2f(u.w) };
#pragma unroll
        for (int j = 0; j < 4; ++j) {
            const int t = (e + j) / 25, v = (e + j) % 25;
            yl[t * RS + v] = f[j];
        }
    }
    if (tid < KW) a0s[tid] = att0[c * KW + tid];
    __syncthreads();

    const int t0 = tid * 2, t1 = t0 + 1;

    float4 yc0[7], yc1[7];
    {
        const float4* r0 = (const float4*)&yl[t0 * RS];
        const float4* r1 = (const float4*)&yl[t1 * RS];
#pragma unroll
        for (int k = 0; k < 7; ++k) { yc0[k] = r0[k]; yc1[k] = r1[k]; }
    }

    float s0[KW], s1[KW];
#pragma unroll
    for (int u = 0; u < KW; ++u) { s0[u] = 0.f; s1[u] = 0.f; }

#pragma unroll
    for (int j = 0; j < 10; ++j) {
        const int r = t0 - PAD + j;
        if (r >= 0 && r < TT) {
            const float4* rw = (const float4*)&yl[r * RS];
            float d0 = 0.f, d1 = 0.f;
#pragma unroll
            for (int k = 0; k < 7; ++k) {
                const float4 q = rw[k];
                d0 = fmaf(q.x, yc0[k].x, d0); d0 = fmaf(q.y, yc0[k].y, d0);
                d0 = fmaf(q.z, yc0[k].z, d0); d0 = fmaf(q.w, yc0[k].w, d0);
                d1 = fmaf(q.x, yc1[k].x, d1); d1 = fmaf(q.y, yc1[k].y, d1);
                d1 = fmaf(q.z, yc1[k].z, d1); d1 = fmaf(q.w, yc1[k].w, d1);
            }
            if (j <= 8) s0[j]     = d0 * (1.f / (float)VV);
            if (j >= 1) s1[j - 1] = d1 * (1.f / (float)VV);
        }
    }

    float aw0[KW], aw1[KW];
    {
        float m0 = s0[0], m1 = s1[0];
#pragma unroll
        for (int u = 1; u < KW; ++u) { m0 = fmaxf(m0, s0[u]); m1 = fmaxf(m1, s1[u]); }
        float d0 = 0.f, d1 = 0.f;
#pragma unroll
        for (int u = 0; u < KW; ++u) {
            aw0[u] = __expf(s0[u] - m0); d0 += aw0[u];
            aw1[u] = __expf(s1[u] - m1); d1 += aw1[u];
        }
        const float i0 = 1.f / d0, i1 = 1.f / d1;
#pragma unroll
        for (int u = 0; u < KW; ++u) {
            aw0[u] = aw0[u] * i0 + a0s[u];
            aw1[u] = aw1[u] * i1 + a0s[u];
        }
    }

    float4 o0[7], o1[7];
#pragma unroll
    for (int k = 0; k < 7; ++k) {
        o0[k] = make_float4(0.f, 0.f, 0.f, 0.f);
        o1[k] = make_float4(0.f, 0.f, 0.f, 0.f);
    }
#pragma unroll
    for (int j = 0; j < 10; ++j) {
        const int r = t0 - PAD + j;
        if (r >= 0 && r < TT) {
            const float4* rw = (const float4*)&yl[r * RS];
#pragma unroll
            for (int k = 0; k < 7; ++k) {
                const float4 q = rw[k];
                if (j <= 8) {
                    const float a = aw0[j];
                    o0[k].x = fmaf(a, q.x, o0[k].x); o0[k].y = fmaf(a, q.y, o0[k].y);
                    o0[k].z = fmaf(a, q.z, o0[k].z); o0[k].w = fmaf(a, q.w, o0[k].w);
                }
                if (j >= 1) {
                    const float a = aw1[j - 1];
                    o1[k].x = fmaf(a, q.x, o1[k].x); o1[k].y = fmaf(a, q.y, o1[k].y);
                    o1[k].z = fmaf(a, q.z, o1[k].z); o1[k].w = fmaf(a, q.w, o1[k].w);
                }
            }
        }
    }

    __syncthreads();
    {
        float* op0 = &yl[t0 * VV];
        float* op1 = &yl[t1 * VV];
#pragma unroll
        for (int k = 0; k < 6; ++k) {
            op0[4*k+0] = o0[k].x; op0[4*k+1] = o0[k].y; op0[4*k+2] = o0[k].z; op0[4*k+3] = o0[k].w;
            op1[4*k+0] = o1[k].x; op1[4*k+1] = o1[k].y; op1[4*k+2] = o1[k].z; op1[4*k+3] = o1[k].w;
        }
        op0[24] = o0[6].x;
        op1[24] = o1[6].x;
    }
    __syncthreads();
    {
        float4* og = (float4*)(out + (size_t)nc * TV);
        const float4* yl4 = (const float4*)yl;
        for (int i = tid; i < TV / 4; i += 128) og[i] = yl4[i];
    }
}

extern "C" void kernel_launch(void* const* d_in, const int* in_sizes, int n_in,
                              void* d_out, int out_size, void* d_ws, size_t ws_size,
                              hipStream_t stream)
{
    const float* x     = (const float*)d_in[0];
    const float* w     = (const float*)d_in[1];
    const float* cb    = (const float*)d_in[2];
    const float* gamma = (const float*)d_in[3];
    const float* beta  = (const float*)d_in[4];
    const float* rm    = (const float*)d_in[5];
    const float* rv    = (const float*)d_in[6];
    const float* att0  = (const float*)d_in[7];
    float* out = (float*)d_out;
    unsigned short* y = (unsigned short*)d_ws;   // 16*128*6400*2 = 26.2 MB bf16 scratch

    dim3 gA(TV / 128, 16);   // 50 x 16
    conv_mfma<<<gA, 256, 0, stream>>>(x, w, cb, gamma, beta, rm, rv, y);

    dim3 gB(16 * COUT);
    attn_kernel<<<gB, 128, 0, stream>>>(y, att0, out);
}